// Round 4
// baseline (284.533 us; speedup 1.0000x reference)
//
#include <hip/hip_runtime.h>
#include <hip/hip_bf16.h>

// Problem constants
#define B_     16384
#define NS_    26
#define ND_    13
#define V_     100000
#define H_     400
#define NP     448          // padded N and K for every DNN layer
#define MT     64           // rows per fused block
#define ASTR   456          // act LDS row stride in BYTES (448 + 8 pad)
#define WCHB   (448 * 64)   // bytes per weight k-chunk [448 n][64 k] fp8

// LDS layout (bytes)
#define ACT_OFF   0
#define WBUF_OFF  (MT * ASTR)                  // 29184
#define FMV_OFF   (WBUF_OFF + 2 * WCHB)        // 86528
#define DOT_OFF   (FMV_OFF + 256)              // 86784
#define LDSB      (DOT_OFF + 256)              // 87040

// Scaling (all powers of 2, algebra exact in fp32 epilogues):
//  act0 sparse cols x 2^12, dense cols x 2^6; weights x 2^12
//  (layer0 dense-row weights x 2^18 to unify); acc0 = 2^24 * true
//  A1 = 2^21, A2 = 2^31 -> f0 = 2^21/2^24 = 0.125, f1 = 2^31/2^33 = 0.25,
//  final g = 2^-43.
#define SC_A1   2097152.0f
#define SC_A2   2147483648.0f
#define SC_F0   0.125f
#define SC_F1   0.25f
#define SC_G    1.1368683772161603e-13f

typedef float f32x4 __attribute__((ext_vector_type(4)));

__device__ __forceinline__ unsigned char f2fp8(float v) {
  int pk = __builtin_amdgcn_cvt_pk_fp8_f32(v, v, 0, false);
  return (unsigned char)(pk & 0xff);
}

// ---------------------------------------------------------------------------
// prep_w: blocks [0,147): 64x64 LDS-tiled transpose of W0/W1/W2 (fp32 [K][400]
// row-major) -> fp8 Wt[n][448] = Q8(W[k][n] * scale(layer,k)), coalesced both
// ways. Block 147: scale/pad biases + W_out.
// ---------------------------------------------------------------------------
__global__ __launch_bounds__(256) void prep_w(
    const float* __restrict__ W0, const float* __restrict__ W1,
    const float* __restrict__ W2, const float* __restrict__ b0,
    const float* __restrict__ b1, const float* __restrict__ b2,
    const float* __restrict__ Wout,
    unsigned char* __restrict__ W0t, unsigned char* __restrict__ W1t,
    unsigned char* __restrict__ W2t, float* __restrict__ b0p,
    float* __restrict__ b1p, float* __restrict__ b2p,
    float* __restrict__ woutp) {
  const int blk = blockIdx.x;
  const int tid = threadIdx.x;
  if (blk < 147) {
    const int layer = blk / 49;
    const int t = blk - layer * 49;
    const int k0 = (t / 7) * 64, n0 = (t - (t / 7) * 7) * 64;
    const float* W = (layer == 0) ? W0 : (layer == 1) ? W1 : W2;
    unsigned char* Wt = (layer == 0) ? W0t : (layer == 1) ? W1t : W2t;
    const int Kdim = (layer == 0) ? 429 : 400;
    __shared__ float tile[64][65];
#pragma unroll
    for (int p = 0; p < 16; ++p) {
      int kk = p * 4 + (tid >> 6);
      int k = k0 + kk;
      int n = n0 + (tid & 63);
      float v = (k < Kdim && n < H_) ? W[k * H_ + n] : 0.f;
      tile[kk][tid & 63] = v;
    }
    __syncthreads();
#pragma unroll
    for (int p = 0; p < 4; ++p) {
      int nn = p * 16 + (tid >> 4);
      int n = n0 + nn;
      int k4 = (tid & 15) * 4;
      float sc[4];
#pragma unroll
      for (int i = 0; i < 4; ++i) {
        int kabs = k0 + k4 + i;
        sc[i] = (layer == 0 && kabs >= 416) ? 262144.0f : 4096.0f;
      }
      float v0 = tile[k4 + 0][nn] * sc[0];
      float v1 = tile[k4 + 1][nn] * sc[1];
      float v2 = tile[k4 + 2][nn] * sc[2];
      float v3 = tile[k4 + 3][nn] * sc[3];
      int w = __builtin_amdgcn_cvt_pk_fp8_f32(v0, v1, 0, false);
      w = __builtin_amdgcn_cvt_pk_fp8_f32(v2, v3, w, true);
      *(unsigned int*)(Wt + (size_t)n * NP + k0 + k4) = (unsigned int)w;
    }
  } else {
    // biases + wout: 4 x 448 values
    for (int it = 0; it < 7; ++it) {
      int j = it * 256 + tid;
      if (j < NP)              b0p[j]          = (j < H_) ? b0[j] * SC_A1 : 0.f;
      else if (j < 2 * NP)     b1p[j - NP]     = (j - NP < H_) ? b1[j - NP] * SC_A2 : 0.f;
      else if (j < 3 * NP)     b2p[j - 2*NP]   = (j - 2*NP < H_) ? b2[j - 2*NP] : 0.f;
      else if (j < 4 * NP)     woutp[j - 3*NP] = (j - 3*NP < H_) ? Wout[j - 3*NP] : 0.f;
    }
  }
}

// ---------------------------------------------------------------------------
// Stage one fp8 weight k-chunk [448 n][64 k] into LDS via global_load_lds
// width=16. LDS dest is wave-uniform base + lane*16 (required semantics).
// ---------------------------------------------------------------------------
__device__ __forceinline__ void stage_w_chunk(
    const unsigned char* __restrict__ Wt, int kt, unsigned char* wb,
    int wave, int lane) {
#pragma unroll
  for (int i = 0; i < 7; ++i) {
    int sbase = i * 256 + wave * 64;   // wave-uniform 16B-slot base
    int s = sbase + lane;
    int n = s >> 2, g = s & 3;
    const unsigned char* gp = Wt + (size_t)n * NP + kt * 64 + g * 16;
    unsigned char* lp = wb + (size_t)sbase * 16;
    __builtin_amdgcn_global_load_lds(
        (const __attribute__((address_space(1))) unsigned int*)gp,
        (__attribute__((address_space(3))) unsigned int*)lp, 16, 0, 0);
  }
}

// ---------------------------------------------------------------------------
// fused_all: each block owns 64 batch rows end-to-end.
//  phase 1: gather emb2 (float4-coalesced, 4 threads/row) -> fp8 act in LDS;
//           FM linear + cross in fp32 -> fmv[] in LDS.
//  phase 2: 3 fp8 MFMA layers, act updated in place; weight chunks double-
//           buffered via global_load_lds.
//  phase 3: layer-2 epilogue fuses h2 . W_out (LDS atomics), single out write.
// ---------------------------------------------------------------------------
__global__ __launch_bounds__(256, 1) void fused_all(
    const int* __restrict__ Xs, const float* __restrict__ Xd,
    const float* __restrict__ emb1, const float* __restrict__ emb2,
    const float* __restrict__ linw, const float* __restrict__ bias,
    const unsigned char* __restrict__ W0t, const unsigned char* __restrict__ W1t,
    const unsigned char* __restrict__ W2t,
    const float* __restrict__ b0p, const float* __restrict__ b1p,
    const float* __restrict__ b2p, const float* __restrict__ woutp,
    float* __restrict__ out) {
  extern __shared__ char smem[];
  unsigned char* act  = (unsigned char*)(smem + ACT_OFF);   // [64][456] fp8
  unsigned char* wbuf = (unsigned char*)(smem + WBUF_OFF);  // 2 x [448][64] fp8
  float* fmv  = (float*)(smem + FMV_OFF);                   // [64]
  float* dotv = (float*)(smem + DOT_OFF);                   // [64]

  const int tid  = threadIdx.x;
  const int wave = tid >> 6;
  const int lane = tid & 63;
  const int quad = lane >> 4;
  const int l16  = lane & 15;
  const int r0   = blockIdx.x * MT;

  // kick off layer-0 chunk-0 DMA immediately (overlaps the gather phase)
  stage_w_chunk(W0t, 0, wbuf, wave, lane);

  // ---- phase 1: FM + act build. lane = r*4 + t4: 16 rows/wave, 4 thr/row ----
  {
    if (tid < 64) dotv[tid] = 0.f;
    const int r   = lane >> 2;
    const int t4  = lane & 3;
    const int row = wave * 16 + r;
    const int gr  = r0 + row;
    const int* xs = Xs + gr * NS_;

    f32x4 sum = {0.f, 0.f, 0.f, 0.f}, sq = {0.f, 0.f, 0.f, 0.f};
#pragma unroll
    for (int f = 0; f < NS_; ++f) {
      int idx = xs[f];
      f32x4 v = *(const f32x4*)(emb2 + ((size_t)f * V_ + idx) * 16 + t4 * 4);
      sum += v;
      sq  += v * v;
      int pk = __builtin_amdgcn_cvt_pk_fp8_f32(v[0] * 4096.f, v[1] * 4096.f, 0, false);
      pk = __builtin_amdgcn_cvt_pk_fp8_f32(v[2] * 4096.f, v[3] * 4096.f, pk, true);
      *(unsigned int*)(act + row * ASTR + f * 16 + t4 * 4) = (unsigned int)pk;
    }

    float lin = 0.f;
    for (int f = t4; f < NS_; f += 4)
      lin += emb1[(size_t)f * V_ + xs[f]];

    // zero pad cols 416..447 (each t4 covers e = t4 mod 4)
    for (int e = 416 + t4; e < NP; e += 4) act[row * ASTR + e] = 0;
    // dense features: fp32 linear + fp8 (x 2^6) into act
    for (int e = t4; e < ND_; e += 4) {
      float xd = Xd[gr * ND_ + e];
      lin += xd * linw[e];
      act[row * ASTR + 416 + e] = f2fp8(xd * 64.f);
    }

    f32x4 c4 = sum * sum - sq;
    float fm = 0.5f * (c4[0] + c4[1] + c4[2] + c4[3]) + lin;
    fm += __shfl_xor(fm, 1, 64);
    fm += __shfl_xor(fm, 2, 64);
    if (t4 == 0) fmv[row] = fm + bias[0];
  }

  // ---- phase 2/3: three fp8 layers ----
  const unsigned char* Wl[3] = {W0t, W1t, W2t};

  for (int layer = 0; layer < 3; ++layer) {
    f32x4 acc[4][7] = {};

    for (int kt = 0; kt < 7; ++kt) {
      __syncthreads();  // chunk kt resident; other buffer free; act writes visible
      if (kt < 6)
        stage_w_chunk(Wl[layer], kt + 1, wbuf + ((kt + 1) & 1) * WCHB, wave, lane);
      const unsigned char* wb = wbuf + (kt & 1) * WCHB;

#pragma unroll
      for (int h = 0; h < 2; ++h) {
        long long av[4];
#pragma unroll
        for (int mt = 0; mt < 4; ++mt)
          av[mt] = *(const long long*)(act + (mt * 16 + l16) * ASTR + kt * 64 + h * 32 + quad * 8);
#pragma unroll
        for (int nt = 0; nt < 7; ++nt) {
          long long bv = *(const long long*)(wb + (wave * 112 + nt * 16 + l16) * 64 + h * 32 + quad * 8);
#pragma unroll
          for (int mt = 0; mt < 4; ++mt)
            acc[mt][nt] = __builtin_amdgcn_mfma_f32_16x16x32_fp8_fp8(av[mt], bv, acc[mt][nt], 0, 0, 0);
        }
      }
    }

    __syncthreads();  // all waves done reading act + wbuf for this layer

    if (layer < 2) {
      stage_w_chunk(Wl[layer + 1], 0, wbuf, wave, lane);  // overlaps epilogue
      const float fs = (layer == 0) ? SC_F0 : SC_F1;
      const float* bl = (layer == 0) ? b0p : b1p;
#pragma unroll
      for (int nt = 0; nt < 7; ++nt) {
        int col = wave * 112 + nt * 16 + l16;
        float bz = bl[col];
#pragma unroll
        for (int mt = 0; mt < 4; ++mt) {
#pragma unroll
          for (int r = 0; r < 4; ++r) {
            float v = acc[mt][nt][r] * fs + bz;
            v = v > 0.f ? v : 0.f;
            act[(mt * 16 + quad * 4 + r) * ASTR + col] = f2fp8(v);
          }
        }
      }
    } else {
      float wsum[4][4] = {};
#pragma unroll
      for (int nt = 0; nt < 7; ++nt) {
        int col = wave * 112 + nt * 16 + l16;
        float bz = b2p[col];
        float wv = woutp[col];
#pragma unroll
        for (int mt = 0; mt < 4; ++mt) {
#pragma unroll
          for (int r = 0; r < 4; ++r) {
            float v = acc[mt][nt][r] * SC_G + bz;
            v = v > 0.f ? v : 0.f;
            wsum[mt][r] += v * wv;
          }
        }
      }
#pragma unroll
      for (int mt = 0; mt < 4; ++mt) {
#pragma unroll
        for (int r = 0; r < 4; ++r) {
          float s = wsum[mt][r];
          s += __shfl_xor(s, 1, 64);
          s += __shfl_xor(s, 2, 64);
          s += __shfl_xor(s, 4, 64);
          s += __shfl_xor(s, 8, 64);
          if (l16 == 0) atomicAdd(&dotv[mt * 16 + quad * 4 + r], s);
        }
      }
    }
  }

  __syncthreads();
  if (tid < 64) out[r0 + tid] = fmv[tid] + dotv[tid];
}

// ---------------------------------------------------------------------------
extern "C" void kernel_launch(void* const* d_in, const int* in_sizes, int n_in,
                              void* d_out, int out_size, void* d_ws, size_t ws_size,
                              hipStream_t stream) {
  const int*   Xs   = (const int*)d_in[0];
  const float* Xd   = (const float*)d_in[1];
  const float* emb1 = (const float*)d_in[2];
  const float* emb2 = (const float*)d_in[3];
  const float* linw = (const float*)d_in[4];
  const float* bias = (const float*)d_in[5];
  const float* W0   = (const float*)d_in[6];
  const float* b0   = (const float*)d_in[7];
  const float* W1   = (const float*)d_in[8];
  const float* b1   = (const float*)d_in[9];
  const float* W2   = (const float*)d_in[10];
  const float* b2   = (const float*)d_in[11];
  const float* Wout = (const float*)d_in[12];
  float* out = (float*)d_out;

  char* ws = (char*)d_ws;
  const size_t WSZ = (size_t)NP * NP;   // 200704 bytes per fp8 weight
  unsigned char* W0t = (unsigned char*)(ws);
  unsigned char* W1t = (unsigned char*)(ws + WSZ);
  unsigned char* W2t = (unsigned char*)(ws + 2 * WSZ);
  float* b0p   = (float*)(ws + 3 * WSZ);
  float* b1p   = (float*)(ws + 3 * WSZ + 1792);
  float* b2p   = (float*)(ws + 3 * WSZ + 2 * 1792);
  float* woutp = (float*)(ws + 3 * WSZ + 3 * 1792);

  (void)hipFuncSetAttribute((const void*)fused_all,
                            hipFuncAttributeMaxDynamicSharedMemorySize, LDSB);

  prep_w<<<148, 256, 0, stream>>>(W0, W1, W2, b0, b1, b2, Wout,
                                  W0t, W1t, W2t, b0p, b1p, b2p, woutp);

  fused_all<<<B_ / MT, 256, LDSB, stream>>>(
      Xs, Xd, emb1, emb2, linw, bias, W0t, W1t, W2t,
      b0p, b1p, b2p, woutp, out);
}

// Round 5
// 274.293 us; speedup vs baseline: 1.0373x; 1.0373x over previous
//
#include <hip/hip_runtime.h>
#include <hip/hip_bf16.h>

// Problem constants
#define B_     16384
#define NS_    26
#define ND_    13
#define V_     100000
#define H_     400
#define NP     448          // padded N and K for every DNN layer
#define MT     64           // rows per fused block
#define ASTR   456          // act LDS row stride in BYTES (448 + 8; /4=114≡18 mod 32 -> 16-bank spread)
#define WCHB   (448 * 64)   // bytes per weight k-chunk [448 n][64 k] fp8
#define WQTR   (112 * 64)   // per-wave quarter of a chunk (7168 B)

// LDS layout (bytes)
#define ACT_OFF   0
#define WBUF_OFF  (MT * ASTR)                  // 29184
#define FMV_OFF   (WBUF_OFF + 2 * WCHB)        // 86528
#define DOT_OFF   (FMV_OFF + 256)              // 86784
#define LDSB      (DOT_OFF + 256)              // 87040

// s_waitcnt immediates: vmcnt | expcnt<<4 | lgkmcnt<<8 (gfx9 encoding)
#define WAIT_VM7  0x0F77    // vmcnt(7)  lgkm(15) exp(7)
#define WAIT_VM0  0x0F70    // vmcnt(0)  lgkm(15) exp(7)

// Scaling (all powers of 2, algebra exact in fp32 epilogues):
//  act0 sparse cols x 2^12, dense cols x 2^6; weights x 2^12
//  (layer0 dense-row weights x 2^18 to unify); acc0 = 2^24 * true
//  A1 = 2^21, A2 = 2^31 -> f0 = 2^-3, f1 = 2^-2, final g = 2^-43.
#define SC_A1   2097152.0f
#define SC_A2   2147483648.0f
#define SC_F0   0.125f
#define SC_F1   0.25f
#define SC_G    1.1368683772161603e-13f

typedef float f32x4 __attribute__((ext_vector_type(4)));

__device__ __forceinline__ unsigned char f2fp8(float v) {
  int pk = __builtin_amdgcn_cvt_pk_fp8_f32(v, v, 0, false);
  return (unsigned char)(pk & 0xff);
}

// ---------------------------------------------------------------------------
// prep_w: blocks [0,147): 64x64 LDS-tiled transpose of W0/W1/W2 (fp32 [K][400]
// row-major) -> fp8 Wt[n][448] = Q8(W[k][n] * scale(layer,k)), coalesced both
// ways. Block 147: scale/pad biases + W_out.  (unchanged from R4, validated)
// ---------------------------------------------------------------------------
__global__ __launch_bounds__(256) void prep_w(
    const float* __restrict__ W0, const float* __restrict__ W1,
    const float* __restrict__ W2, const float* __restrict__ b0,
    const float* __restrict__ b1, const float* __restrict__ b2,
    const float* __restrict__ Wout,
    unsigned char* __restrict__ W0t, unsigned char* __restrict__ W1t,
    unsigned char* __restrict__ W2t, float* __restrict__ b0p,
    float* __restrict__ b1p, float* __restrict__ b2p,
    float* __restrict__ woutp) {
  const int blk = blockIdx.x;
  const int tid = threadIdx.x;
  if (blk < 147) {
    const int layer = blk / 49;
    const int t = blk - layer * 49;
    const int k0 = (t / 7) * 64, n0 = (t - (t / 7) * 7) * 64;
    const float* W = (layer == 0) ? W0 : (layer == 1) ? W1 : W2;
    unsigned char* Wt = (layer == 0) ? W0t : (layer == 1) ? W1t : W2t;
    const int Kdim = (layer == 0) ? 429 : 400;
    __shared__ float tile[64][65];
#pragma unroll
    for (int p = 0; p < 16; ++p) {
      int kk = p * 4 + (tid >> 6);
      int k = k0 + kk;
      int n = n0 + (tid & 63);
      float v = (k < Kdim && n < H_) ? W[k * H_ + n] : 0.f;
      tile[kk][tid & 63] = v;
    }
    __syncthreads();
#pragma unroll
    for (int p = 0; p < 4; ++p) {
      int nn = p * 16 + (tid >> 4);
      int n = n0 + nn;
      int k4 = (tid & 15) * 4;
      float sc[4];
#pragma unroll
      for (int i = 0; i < 4; ++i) {
        int kabs = k0 + k4 + i;
        sc[i] = (layer == 0 && kabs >= 416) ? 262144.0f : 4096.0f;
      }
      float v0 = tile[k4 + 0][nn] * sc[0];
      float v1 = tile[k4 + 1][nn] * sc[1];
      float v2 = tile[k4 + 2][nn] * sc[2];
      float v3 = tile[k4 + 3][nn] * sc[3];
      int w = __builtin_amdgcn_cvt_pk_fp8_f32(v0, v1, 0, false);
      w = __builtin_amdgcn_cvt_pk_fp8_f32(v2, v3, w, true);
      *(unsigned int*)(Wt + (size_t)n * NP + k0 + k4) = (unsigned int)w;
    }
  } else {
    for (int it = 0; it < 7; ++it) {
      int j = it * 256 + tid;
      if (j < NP)              b0p[j]          = (j < H_) ? b0[j] * SC_A1 : 0.f;
      else if (j < 2 * NP)     b1p[j - NP]     = (j - NP < H_) ? b1[j - NP] * SC_A2 : 0.f;
      else if (j < 3 * NP)     b2p[j - 2*NP]   = (j - 2*NP < H_) ? b2[j - 2*NP] : 0.f;
      else if (j < 4 * NP)     woutp[j - 3*NP] = (j - 3*NP < H_) ? Wout[j - 3*NP] : 0.f;
    }
  }
}

// ---------------------------------------------------------------------------
// Per-wave weight staging: wave w DMAs ONLY its own n-range [w*112, w*112+112)
// into its private quarter of the chunk buffer -> no cross-wave wbuf deps ->
// no barriers in the K-loop. 16B granules XOR-swizzled on the *source* side
// (slot s holds granule g = (s&3) ^ ((n_local>>1)&3)) so b64 reads spread
// across ~16+ banks instead of 8 (row stride 64B is pathological unswizzled).
// ---------------------------------------------------------------------------
__device__ __forceinline__ void stage_w_chunk(
    const unsigned char* __restrict__ Wt, int kt, unsigned char* wb,
    int wave, int lane) {
  const unsigned char* wrow = Wt + (size_t)(wave * 112) * NP + kt * 64;
  unsigned char* lbase = wb + wave * WQTR;
#pragma unroll
  for (int i = 0; i < 7; ++i) {
    int s = i * 64 + lane;
    int nl = s >> 2;
    int g = (s & 3) ^ ((nl >> 1) & 3);
    const unsigned char* gp = wrow + (size_t)nl * NP + g * 16;
    unsigned char* lp = lbase + (size_t)(i * 64) * 16;   // wave-uniform + lane*16
    __builtin_amdgcn_global_load_lds(
        (const __attribute__((address_space(1))) unsigned int*)gp,
        (__attribute__((address_space(3))) unsigned int*)lp, 16, 0, 0);
  }
}

// ---------------------------------------------------------------------------
// fused_all: each block owns 64 batch rows end-to-end.
//  phase 1: gather emb2 (float4, 4 thr/row) -> fp8 act in LDS; FM in fp32.
//  phase 2: 3 fp8 MFMA layers, act in place; weight chunks double-buffered,
//           K-loop barrier-free with per-wave s_waitcnt vmcnt(7).
//  phase 3: layer-2 epilogue fuses h2 . W_out; single out write per row.
// ---------------------------------------------------------------------------
__global__ __launch_bounds__(256, 1) void fused_all(
    const int* __restrict__ Xs, const float* __restrict__ Xd,
    const float* __restrict__ emb1, const float* __restrict__ emb2,
    const float* __restrict__ linw, const float* __restrict__ bias,
    const unsigned char* __restrict__ W0t, const unsigned char* __restrict__ W1t,
    const unsigned char* __restrict__ W2t,
    const float* __restrict__ b0p, const float* __restrict__ b1p,
    const float* __restrict__ b2p, const float* __restrict__ woutp,
    float* __restrict__ out) {
  extern __shared__ char smem[];
  unsigned char* act  = (unsigned char*)(smem + ACT_OFF);   // [64][456] fp8
  unsigned char* wbuf = (unsigned char*)(smem + WBUF_OFF);  // 2 x [4 waves][112][64]
  float* fmv  = (float*)(smem + FMV_OFF);                   // [64]
  float* dotv = (float*)(smem + DOT_OFF);                   // [64]

  const int tid  = threadIdx.x;
  const int wave = tid >> 6;
  const int lane = tid & 63;
  const int quad = lane >> 4;
  const int l16  = lane & 15;
  const int r0   = blockIdx.x * MT;

  // kick off layer-0 chunk-0 DMA immediately (overlaps the gather phase)
  stage_w_chunk(W0t, 0, wbuf, wave, lane);

  // ---- phase 1: FM + act build. lane = r*4 + t4: 16 rows/wave, 4 thr/row ----
  {
    if (tid < 64) dotv[tid] = 0.f;
    const int r   = lane >> 2;
    const int t4  = lane & 3;
    const int row = wave * 16 + r;
    const int gr  = r0 + row;
    const int* xs = Xs + gr * NS_;

    f32x4 sum = {0.f, 0.f, 0.f, 0.f}, sq = {0.f, 0.f, 0.f, 0.f};
#pragma unroll
    for (int f = 0; f < NS_; ++f) {
      int idx = xs[f];
      f32x4 v = *(const f32x4*)(emb2 + ((size_t)f * V_ + idx) * 16 + t4 * 4);
      sum += v;
      sq  += v * v;
      int pk = __builtin_amdgcn_cvt_pk_fp8_f32(v[0] * 4096.f, v[1] * 4096.f, 0, false);
      pk = __builtin_amdgcn_cvt_pk_fp8_f32(v[2] * 4096.f, v[3] * 4096.f, pk, true);
      *(unsigned int*)(act + row * ASTR + f * 16 + t4 * 4) = (unsigned int)pk;
    }

    float lin = 0.f;
    for (int f = t4; f < NS_; f += 4)
      lin += emb1[(size_t)f * V_ + xs[f]];

    for (int e = 416 + t4; e < NP; e += 4) act[row * ASTR + e] = 0;
    for (int e = t4; e < ND_; e += 4) {
      float xd = Xd[gr * ND_ + e];
      lin += xd * linw[e];
      act[row * ASTR + 416 + e] = f2fp8(xd * 64.f);
    }

    f32x4 c4 = sum * sum - sq;
    float fm = 0.5f * (c4[0] + c4[1] + c4[2] + c4[3]) + lin;
    fm += __shfl_xor(fm, 1, 64);
    fm += __shfl_xor(fm, 2, 64);
    if (t4 == 0) fmv[row] = fm + bias[0];
  }

  __syncthreads();  // act visible to all waves; also drains chunk-0 DMA

  const unsigned char* Wl[3] = {W0t, W1t, W2t};

  for (int layer = 0; layer < 3; ++layer) {
    const unsigned char* Wt = Wl[layer];
    const unsigned char* wq = wbuf + wave * WQTR;   // this wave's quarter
    f32x4 acc[4][7] = {};

    // barrier-free K-loop: double-buffered chunks, per-wave vmcnt gating
    for (int kt = 0; kt < 7; ++kt) {
      if (kt < 6) {
        stage_w_chunk(Wt, kt + 1, wbuf + ((kt + 1) & 1) * WCHB, wave, lane);
        __builtin_amdgcn_s_waitcnt(WAIT_VM7);  // chunk kt resident; kt+1 in flight
      } else {
        __builtin_amdgcn_s_waitcnt(WAIT_VM0);  // last chunk of layer
      }
      __builtin_amdgcn_sched_barrier(0);       // keep ds_reads below the wait
      const unsigned char* wb = wq + (kt & 1) * WCHB;

#pragma unroll
      for (int h = 0; h < 2; ++h) {
        long long av[4];
#pragma unroll
        for (int mt = 0; mt < 4; ++mt)
          av[mt] = *(const long long*)(act + (mt * 16 + l16) * ASTR + kt * 64 + h * 32 + quad * 8);
#pragma unroll
        for (int nt = 0; nt < 7; ++nt) {
          int nl = nt * 16 + l16;
          int sw = (2 * h + (quad >> 1)) ^ ((nl >> 1) & 3);
          long long bv = *(const long long*)(wb + nl * 64 + sw * 16 + (quad & 1) * 8);
#pragma unroll
          for (int mt = 0; mt < 4; ++mt)
            acc[mt][nt] = __builtin_amdgcn_mfma_f32_16x16x32_fp8_fp8(av[mt], bv, acc[mt][nt], 0, 0, 0);
        }
      }
    }

    // prefetch next layer's chunk 0 before the barrier (drained there; resident
    // for kt=0 of the next layer)
    if (layer < 2) stage_w_chunk(Wl[layer + 1], 0, wbuf, wave, lane);

    __syncthreads();  // all waves done reading act for this layer

    if (layer < 2) {
      const float fs = (layer == 0) ? SC_F0 : SC_F1;
      const float* bl = (layer == 0) ? b0p : b1p;
#pragma unroll
      for (int nt = 0; nt < 7; ++nt) {
        int col = wave * 112 + nt * 16 + l16;
        float bz = bl[col];
#pragma unroll
        for (int mt = 0; mt < 4; ++mt) {
#pragma unroll
          for (int r = 0; r < 4; ++r) {
            float v = acc[mt][nt][r] * fs + bz;
            v = v > 0.f ? v : 0.f;
            act[(mt * 16 + quad * 4 + r) * ASTR + col] = f2fp8(v);
          }
        }
      }
    } else {
      float wsum[4][4] = {};
#pragma unroll
      for (int nt = 0; nt < 7; ++nt) {
        int col = wave * 112 + nt * 16 + l16;
        float bz = b2p[col];
        float wv = woutp[col];
#pragma unroll
        for (int mt = 0; mt < 4; ++mt) {
#pragma unroll
          for (int r = 0; r < 4; ++r) {
            float v = acc[mt][nt][r] * SC_G + bz;
            v = v > 0.f ? v : 0.f;
            wsum[mt][r] += v * wv;
          }
        }
      }
#pragma unroll
      for (int mt = 0; mt < 4; ++mt) {
#pragma unroll
        for (int r = 0; r < 4; ++r) {
          float s = wsum[mt][r];
          s += __shfl_xor(s, 1, 64);
          s += __shfl_xor(s, 2, 64);
          s += __shfl_xor(s, 4, 64);
          s += __shfl_xor(s, 8, 64);
          if (l16 == 0) atomicAdd(&dotv[mt * 16 + quad * 4 + r], s);
        }
      }
    }
    __syncthreads();  // epilogue writes visible before next layer / final read
  }

  if (tid < 64) out[r0 + tid] = fmv[tid] + dotv[tid];
}

// ---------------------------------------------------------------------------
extern "C" void kernel_launch(void* const* d_in, const int* in_sizes, int n_in,
                              void* d_out, int out_size, void* d_ws, size_t ws_size,
                              hipStream_t stream) {
  const int*   Xs   = (const int*)d_in[0];
  const float* Xd   = (const float*)d_in[1];
  const float* emb1 = (const float*)d_in[2];
  const float* emb2 = (const float*)d_in[3];
  const float* linw = (const float*)d_in[4];
  const float* bias = (const float*)d_in[5];
  const float* W0   = (const float*)d_in[6];
  const float* b0   = (const float*)d_in[7];
  const float* W1   = (const float*)d_in[8];
  const float* b1   = (const float*)d_in[9];
  const float* W2   = (const float*)d_in[10];
  const float* b2   = (const float*)d_in[11];
  const float* Wout = (const float*)d_in[12];
  float* out = (float*)d_out;

  char* ws = (char*)d_ws;
  const size_t WSZ = (size_t)NP * NP;   // 200704 bytes per fp8 weight
  unsigned char* W0t = (unsigned char*)(ws);
  unsigned char* W1t = (unsigned char*)(ws + WSZ);
  unsigned char* W2t = (unsigned char*)(ws + 2 * WSZ);
  float* b0p   = (float*)(ws + 3 * WSZ);
  float* b1p   = (float*)(ws + 3 * WSZ + 1792);
  float* b2p   = (float*)(ws + 3 * WSZ + 2 * 1792);
  float* woutp = (float*)(ws + 3 * WSZ + 3 * 1792);

  (void)hipFuncSetAttribute((const void*)fused_all,
                            hipFuncAttributeMaxDynamicSharedMemorySize, LDSB);

  prep_w<<<148, 256, 0, stream>>>(W0, W1, W2, b0, b1, b2, Wout,
                                  W0t, W1t, W2t, b0p, b1p, b2p, woutp);

  fused_all<<<B_ / MT, 256, LDSB, stream>>>(
      Xs, Xd, emb1, emb2, linw, bias, W0t, W1t, W2t,
      b0p, b1p, b2p, woutp, out);
}